// Round 1
// 223.873 us; speedup vs baseline: 1.1990x; 1.1990x over previous
//
#include <hip/hip_runtime.h>
#include <math.h>

// Problem constants (fixed by setup_inputs)
constexpr int K_ = 4, B_ = 8, T_ = 800, C_ = 80, S_ = 128, Z_ = 32;
constexpr int KB_ = K_ * B_;        // 32
constexpr int TC_ = T_ * C_;        // 64000

#define BIGV   1e8f
#define WARP_V 256.0f

// R12 sheared-stream layout (g=8): Q[u][i] = D[i][u - (i>>3)].
// Lane l owns rows 16l..16l+15 = groups m=0 (cols j0 = u-2l) and m=1 (j1 = j0-1).
// Per step the wave reads Q[u][0..799]: lane reads 64B contiguous, wave 3.2KB.
constexpr int NU_   = 900;            // u = j + (i>>3) <= 799 + 99 = 898
constexpr int SLAB_ = NU_ * 800;      // 720,000 floats per problem (92.16 MB total)

__device__ __forceinline__ float sigmoidf_(float v) {
    return 1.f / (1.f + __expf(-v));
}

// ---------------------------------------------------------------- fill j = -1 ghost cells with BIG
// Lanes l<=11 read Q[2l][16l+8..15] = D[i][-1] once (their first step): must be BIG.
__global__ void fill_edge(float* __restrict__ Dm) {
    int kb = blockIdx.x;
    int t = threadIdx.x;
    if (t < 184) {
        int i = 8 + t;     // i in [8, 191]
        Dm[(size_t)kb * SLAB_ + (size_t)((i >> 3) - 1) * 800 + i] = BIGV;
    }
}

// ---------------------------------------------------------------- banded GEMM -> sheared Q (norms fused)
// grid (5, 13, 32): tiles |ti-tj| <= 2 (written band deviation >= 128 > DP corridor 124).
// Epilogue: LDS shear-transpose -> coalesced 256B u-row stores (edge rows predicated).
__global__ __launch_bounds__(256) void gemm_band(const float* __restrict__ mel_iters,
                                                 const float* __restrict__ mel_targets,
                                                 float* __restrict__ Dm) {
    const int kb = blockIdx.z;
    const int b  = kb & 7;
    const int ti = blockIdx.y;
    const int tj = ti + (int)blockIdx.x - 2;
    if ((unsigned)tj > 12u) return;

    const float* __restrict__ Xb = mel_iters + (size_t)kb * TC_;
    const float* __restrict__ Yb = mel_targets + (size_t)b * TC_;

    __shared__ float smem[4615];            // phase1: xa[16][68] | ya[16][68] | x2s[64] | y2s[64]
    float (*xa)[68] = (float(*)[68])smem;   // phase2: Zt[71][65]
    float (*ya)[68] = (float(*)[68])(smem + 1088);
    float* x2s = smem + 2176;
    float* y2s = smem + 2240;

    const int tid = threadIdx.x;
    const int tx = tid & 15, ty = tid >> 4;
    const int i0 = ti * 64, j0 = tj * 64;
    const int lr = tid >> 4;   // 0..15
    const int lc = tid & 15;   // 0..15  (k within chunk)

    float acc[4][4] = {};
    float nsum = 0.f;          // row-norm partial (tid<64: x2 row tid; tid in [64,128): y2)

    for (int kk = 0; kk < C_; kk += 16) {
        __syncthreads();
        #pragma unroll
        for (int q = 0; q < 4; ++q) {
            int row = lr + q * 16;       // 0..63
            int gi = i0 + row;
            xa[lc][row] = (gi < T_) ? sigmoidf_(Xb[(size_t)gi * C_ + kk + lc]) : 0.f;
            int gj = j0 + row;
            ya[lc][row] = (gj < T_) ? sigmoidf_(Yb[(size_t)gj * C_ + kk + lc]) : 0.f;
        }
        __syncthreads();
        if (tid < 64) {
            #pragma unroll
            for (int k = 0; k < 16; ++k) { float v = xa[k][tid]; nsum += v * v; }
        } else if (tid < 128) {
            #pragma unroll
            for (int k = 0; k < 16; ++k) { float v = ya[k][tid - 64]; nsum += v * v; }
        }
        #pragma unroll
        for (int k = 0; k < 16; ++k) {
            float4 av = *(const float4*)&xa[k][ty * 4];
            float4 bv = *(const float4*)&ya[k][tx * 4];
            acc[0][0] += av.x * bv.x; acc[0][1] += av.x * bv.y; acc[0][2] += av.x * bv.z; acc[0][3] += av.x * bv.w;
            acc[1][0] += av.y * bv.x; acc[1][1] += av.y * bv.y; acc[1][2] += av.y * bv.z; acc[1][3] += av.y * bv.w;
            acc[2][0] += av.z * bv.x; acc[2][1] += av.z * bv.y; acc[2][2] += av.z * bv.z; acc[2][3] += av.z * bv.w;
            acc[3][0] += av.w * bv.x; acc[3][1] += av.w * bv.y; acc[3][2] += av.w * bv.z; acc[3][3] += av.w * bv.w;
        }
    }
    if (tid < 64) x2s[tid] = nsum;
    else if (tid < 128) y2s[tid - 64] = nsum;
    __syncthreads();

    // read norms into regs BEFORE LDS reuse
    float xs2[4], ys2[4];
    #pragma unroll
    for (int r = 0; r < 4; ++r) xs2[r] = x2s[ty * 4 + r];
    #pragma unroll
    for (int c = 0; c < 4; ++c) ys2[c] = y2s[tx * 4 + c];
    __syncthreads();

    // stage into sheared LDS tile: Zt[u_rel][iLoc], u_rel = 4tx + c + (ty>>1)
    float* Zt = smem;                     // [71][65]
    const int sb = ty >> 1;
    #pragma unroll
    for (int r = 0; r < 4; ++r)
        #pragma unroll
        for (int c = 0; c < 4; ++c)
            Zt[(4 * tx + c + sb) * 65 + (4 * ty + r)] = xs2[r] + ys2[c] - 2.f * acc[r][c];
    __syncthreads();

    // coalesced u-row stores: u_global = j0 + 8ti + w, 64 contiguous floats at i0
    const int w0 = tid >> 6;              // wave id 0..3
    const int lane = tid & 63;
    const int iGlob = i0 + lane;
    const int sbl = lane >> 3;            // s(i) - 8ti
    const bool iok = iGlob < T_;
    const size_t ub = (size_t)(j0 + 8 * ti) * 800 + iGlob;
    #pragma unroll
    for (int it = 0; it < 18; ++it) {
        int w = w0 + it * 4;
        if (w > 70) break;
        int jrel = w - sbl;
        if (iok && (unsigned)jrel < 64u && (j0 + jrel) < T_)
            Dm[(size_t)kb * SLAB_ + ub + (size_t)w * 800] = Zt[w * 65 + lane];
    }
}

// ---------------------------------------------------------------- single-wave hard-min DTW, r=16, g=8 shear
// One wave per problem: zero barriers/LDS. Lane l rows 16l..16l+15 in two
// independent 8-chains per step.
//
// R13 cell compression: n = min(dg+D, up+D+W, left+D+W) = min3(dg, up+W, left+W) + D.
// Carry BOTH s[i] (raw, feeds diag two steps later) and w[i] = s[i]+W (feeds
// up/left next step): 3 VALU/cell (v_min3 fusion of nested fminf, +D, +W)
// instead of 6. Cross-lane: 1 DPP + cndmask, tin+W derived by one add.
//
// R13 buffering: ring of 6 single-step slots (96 floats live vs 192 for the
// old 3x4-step batches -> no register-pressure copy traffic). Prefetch depth
// 5 steps between issue and s_waitcnt vmcnt(20) (never drained to 0 in loop).
__device__ __forceinline__ float wave_shr1(float x) {
    int v = __builtin_amdgcn_update_dpp(0, __float_as_int(x), 0x138, 0xf, 0xf, true);
    return __int_as_float(v);
}

#define WAITV(n) asm volatile("s_waitcnt vmcnt(" #n ")")

__global__ __launch_bounds__(64, 1) void dtw_wave_kernel(const float* __restrict__ Dm,
                                                         float* __restrict__ dtwv) {
    const int kb = blockIdx.x;
    const int l  = threadIdx.x;
    const int lc = l < 49 ? l : 49;             // lanes 50-63 mirror lane 49
    const bool is_l0 = (l == 0);
    const float* __restrict__ Dd = Dm + (size_t)kb * SLAB_;

    const int ti_l = lc >> 2;
    const int Jlo = ti_l >= 2 ? 64 * (ti_l - 2) : 0;
    const int Jhi = min(799, 64 * ti_l + 191);
    const int lo_u = (Jlo == 0) ? (2 * lc) : (Jlo + 2 * lc + 1);
    const int hi_u = Jhi + 2 * lc + 1;
    const int lofs = lc << 4;

    // DP state: raw values s0..s15 and pre-added w_i = s_i + WARP
    float s0 = BIGV, s1 = BIGV, s2 = BIGV, s3 = BIGV, s4 = BIGV, s5 = BIGV, s6 = BIGV, s7 = BIGV;
    float s8 = BIGV, s9 = BIGV, s10 = BIGV, s11 = BIGV, s12 = BIGV, s13 = BIGV, s14 = BIGV, s15 = BIGV;
    float w0 = BIGV, w1 = BIGV, w2 = BIGV, w3 = BIGV, w4 = BIGV, w5 = BIGV, w6 = BIGV, w7 = BIGV;
    float w8 = BIGV, w9 = BIGV, w10 = BIGV, w11 = BIGV, w12 = BIGV, w13 = BIGV, w14 = BIGV, w15 = BIGV;
    float s7p = BIGV;                           // raw S7 two steps ago
    float tinA = BIGV;                          // lane l-1 raw S15, one step ago
    float tinAW = BIGV;                         // tinA + WARP
    float tinB = is_l0 ? 0.f : BIGV;            // raw, two steps ago (lane0: diag of (0,0))

    auto pref = [&](float4 (&sl)[4], int uu) {
        int uc = uu < lo_u ? lo_u : (uu > hi_u ? hi_u : uu);
        const float* p = Dd + (size_t)uc * 800 + lofs;
        sl[0] = *(const float4*)(p);
        sl[1] = *(const float4*)(p + 4);
        sl[2] = *(const float4*)(p + 8);
        sl[3] = *(const float4*)(p + 12);
    };

    auto step = [&](const float4 (&dq)[4]) {
        const float up7 = s7;                   // raw S7 pre-update (s7p next step)
        float d0 = tinB, uw0 = tinAW;           // chain-0 inputs (diag raw, up+W)
        float d1 = s7p,  uw1 = w7;              // chain-1 inputs (w7 pre-update)
        #define CELLP(SA, WA, DA, SB, WB, DB)                          \
        {   float mA = fminf(fminf(d0, uw0), WA);  /* v_min3 */        \
            float nA = mA + (DA);                                      \
            d0 = SA; SA = nA;                                          \
            float tA = nA + WARP_V; uw0 = tA; WA = tA;                 \
            float mB = fminf(fminf(d1, uw1), WB);                      \
            float nB = mB + (DB);                                      \
            d1 = SB; SB = nB;                                          \
            float tB = nB + WARP_V; uw1 = tB; WB = tB;                 \
        }
        CELLP(s0, w0, dq[0].x, s8,  w8,  dq[2].x);
        CELLP(s1, w1, dq[0].y, s9,  w9,  dq[2].y);
        CELLP(s2, w2, dq[0].z, s10, w10, dq[2].z);
        CELLP(s3, w3, dq[0].w, s11, w11, dq[2].w);
        CELLP(s4, w4, dq[1].x, s12, w12, dq[3].x);
        CELLP(s5, w5, dq[1].y, s13, w13, dq[3].y);
        CELLP(s6, w6, dq[1].z, s14, w14, dq[3].z);
        CELLP(s7, w7, dq[1].w, s15, w15, dq[3].w);
        #undef CELLP
        s7p = up7;
        float hand = wave_shr1(s15);
        tinB = tinA;
        tinA = is_l0 ? BIGV : hand;
        tinAW = tinA + WARP_V;
    };

    float4 q0[4], q1[4], q2[4], q3[4], q4[4], q5[4];
    pref(q0, 0); pref(q1, 1); pref(q2, 2); pref(q3, 3); pref(q4, 4); pref(q5, 5);

    int u = 0;
    for (int g = 0; g < 149; ++g) {             // steps 0..893
        WAITV(20); step(q0); pref(q0, u + 6);
        WAITV(20); step(q1); pref(q1, u + 7);
        WAITV(20); step(q2); pref(q2, u + 8);
        WAITV(20); step(q3); pref(q3, u + 9);
        WAITV(20); step(q4); pref(q4, u + 10);
        WAITV(20); step(q5); pref(q5, u + 11);
        u += 6;
    }
    // u = 894: slots hold steps 894..899 (>=899 clamped duplicates, unused lanes)
    WAITV(20); step(q0);                        // 894
    WAITV(16); step(q1);                        // 895
    WAITV(12); step(q2);                        // 896
    WAITV(8);  step(q3);                        // 897
    WAITV(4);  step(q4);                        // 898: lane 49 s15 = R[800][800]

    if (l == 49) dtwv[kb] = s15;
}

// ---------------------------------------------------------------- finalize (scalars)
__global__ void finalize_kernel(const float* __restrict__ dtwv, const int* __restrict__ mel_lens,
                                const int* __restrict__ src_lens, const float* __restrict__ durations,
                                const float* __restrict__ mus, const float* __restrict__ log_vars,
                                const int* __restrict__ step, float* __restrict__ out) {
    const int lane = threadIdx.x;  // 64 threads, one wave

    float v = (lane < KB_) ? dtwv[lane] : 0.f;
    for (int o = 32; o; o >>= 1) v += __shfl_down(v, o);

    float w = (lane < B_) ? 1.f / (K_ * (float)mel_lens[lane]) : 0.f;
    for (int o = 32; o; o >>= 1) w += __shfl_down(w, o);

    float du = 0.f;
    if (lane < B_) {
        float s = 0.f;
        for (int j = 0; j < S_; ++j) s += durations[lane * S_ + j];
        du = fabsf(s - (float)mel_lens[lane]) / (float)src_lens[lane];
    }
    for (int o = 32; o; o >>= 1) du += __shfl_down(du, o);

    float kl = 0.f;
    for (int j = lane; j < B_ * Z_; j += 64) {
        float muv = mus[j], lv = log_vars[j];
        kl += 1.f + lv - muv * muv - expf(lv);
    }
    for (int o = 32; o; o >>= 1) kl += __shfl_down(kl, o);

    if (lane == 0) {
        float mel_iter_loss = v / (float)B_;
        float mel_loss = mel_iter_loss * (w / (float)B_);
        float dur_loss = 2.0f * du / (float)B_;
        float kl_loss = -0.5f * kl;
        int st = step[0];
        float beta = (st < 2000) ? 0.f : ((st >= 8000) ? 1.f : (float)(st - 2000) / 6000.f);
        out[0] = mel_loss + dur_loss + beta * kl_loss;
        out[1] = mel_loss;
        out[2] = dur_loss;
        out[3] = kl_loss;
        out[4] = beta;
    }
}

// ---------------------------------------------------------------- launch
extern "C" void kernel_launch(void* const* d_in, const int* in_sizes, int n_in,
                              void* d_out, int out_size, void* d_ws, size_t ws_size,
                              hipStream_t stream) {
    const float* mel_iters   = (const float*)d_in[0];
    const float* mel_targets = (const float*)d_in[1];
    const int*   mel_lens    = (const int*)d_in[2];
    const int*   src_lens    = (const int*)d_in[3];
    const float* durations   = (const float*)d_in[4];
    const float* mus         = (const float*)d_in[5];
    const float* log_vars    = (const float*)d_in[6];
    const int*   step        = (const int*)d_in[7];
    float* out = (float*)d_out;

    float* ws   = (float*)d_ws;
    float* Dm   = ws;                              // 32 * 720,000 floats = 92.16 MB
    float* dtwv = Dm + (size_t)KB_ * SLAB_;        //        32

    fill_edge<<<KB_, 192, 0, stream>>>(Dm);

    gemm_band<<<dim3(5, 13, KB_), 256, 0, stream>>>(mel_iters, mel_targets, Dm);

    dtw_wave_kernel<<<KB_, 64, 0, stream>>>(Dm, dtwv);

    finalize_kernel<<<1, 64, 0, stream>>>(dtwv, mel_lens, src_lens, durations, mus, log_vars, step, out);
}

// Round 2
// 223.446 us; speedup vs baseline: 1.2013x; 1.0019x over previous
//
#include <hip/hip_runtime.h>
#include <math.h>

// Problem constants (fixed by setup_inputs)
constexpr int K_ = 4, B_ = 8, T_ = 800, C_ = 80, S_ = 128, Z_ = 32;
constexpr int KB_ = K_ * B_;        // 32
constexpr int TC_ = T_ * C_;        // 64000

#define BIGV   1e8f
#define WARP_V 256.0f

// R12 sheared-stream layout (g=8): Q[u][i] = D[i][u - (i>>3)].
// Lane l owns rows 16l..16l+15 = groups m=0 (cols j0 = u-2l) and m=1 (j1 = j0-1).
// Per step the wave reads Q[u][0..799]: lane reads 64B contiguous, wave 3.2KB.
constexpr int NU_   = 900;            // u = j + (i>>3) <= 799 + 99 = 898
constexpr int SLAB_ = NU_ * 800;      // 720,000 floats per problem (92.16 MB total)

__device__ __forceinline__ float sigmoidf_(float v) {
    return 1.f / (1.f + __expf(-v));
}

// ---------------------------------------------------------------- fill j = -1 ghost cells with BIG
// Lanes l<=11 read Q[2l][16l+8..15] = D[i][-1] once (their first step): must be BIG.
__global__ void fill_edge(float* __restrict__ Dm) {
    int kb = blockIdx.x;
    int t = threadIdx.x;
    if (t < 184) {
        int i = 8 + t;     // i in [8, 191]
        Dm[(size_t)kb * SLAB_ + (size_t)((i >> 3) - 1) * 800 + i] = BIGV;
    }
}

// ---------------------------------------------------------------- banded GEMM -> sheared Q (norms fused)
// grid (5, 13, 32): tiles |ti-tj| <= 2 (written band deviation >= 128 > DP corridor 124).
// Epilogue: LDS shear-transpose -> coalesced 256B u-row stores (edge rows predicated).
__global__ __launch_bounds__(256) void gemm_band(const float* __restrict__ mel_iters,
                                                 const float* __restrict__ mel_targets,
                                                 float* __restrict__ Dm) {
    const int kb = blockIdx.z;
    const int b  = kb & 7;
    const int ti = blockIdx.y;
    const int tj = ti + (int)blockIdx.x - 2;
    if ((unsigned)tj > 12u) return;

    const float* __restrict__ Xb = mel_iters + (size_t)kb * TC_;
    const float* __restrict__ Yb = mel_targets + (size_t)b * TC_;

    __shared__ float smem[4615];            // phase1: xa[16][68] | ya[16][68] | x2s[64] | y2s[64]
    float (*xa)[68] = (float(*)[68])smem;   // phase2: Zt[71][65]
    float (*ya)[68] = (float(*)[68])(smem + 1088);
    float* x2s = smem + 2176;
    float* y2s = smem + 2240;

    const int tid = threadIdx.x;
    const int tx = tid & 15, ty = tid >> 4;
    const int i0 = ti * 64, j0 = tj * 64;
    const int lr = tid >> 4;   // 0..15
    const int lc = tid & 15;   // 0..15  (k within chunk)

    float acc[4][4] = {};
    float nsum = 0.f;          // row-norm partial (tid<64: x2 row tid; tid in [64,128): y2)

    for (int kk = 0; kk < C_; kk += 16) {
        __syncthreads();
        #pragma unroll
        for (int q = 0; q < 4; ++q) {
            int row = lr + q * 16;       // 0..63
            int gi = i0 + row;
            xa[lc][row] = (gi < T_) ? sigmoidf_(Xb[(size_t)gi * C_ + kk + lc]) : 0.f;
            int gj = j0 + row;
            ya[lc][row] = (gj < T_) ? sigmoidf_(Yb[(size_t)gj * C_ + kk + lc]) : 0.f;
        }
        __syncthreads();
        if (tid < 64) {
            #pragma unroll
            for (int k = 0; k < 16; ++k) { float v = xa[k][tid]; nsum += v * v; }
        } else if (tid < 128) {
            #pragma unroll
            for (int k = 0; k < 16; ++k) { float v = ya[k][tid - 64]; nsum += v * v; }
        }
        #pragma unroll
        for (int k = 0; k < 16; ++k) {
            float4 av = *(const float4*)&xa[k][ty * 4];
            float4 bv = *(const float4*)&ya[k][tx * 4];
            acc[0][0] += av.x * bv.x; acc[0][1] += av.x * bv.y; acc[0][2] += av.x * bv.z; acc[0][3] += av.x * bv.w;
            acc[1][0] += av.y * bv.x; acc[1][1] += av.y * bv.y; acc[1][2] += av.y * bv.z; acc[1][3] += av.y * bv.w;
            acc[2][0] += av.z * bv.x; acc[2][1] += av.z * bv.y; acc[2][2] += av.z * bv.z; acc[2][3] += av.z * bv.w;
            acc[3][0] += av.w * bv.x; acc[3][1] += av.w * bv.y; acc[3][2] += av.w * bv.z; acc[3][3] += av.w * bv.w;
        }
    }
    if (tid < 64) x2s[tid] = nsum;
    else if (tid < 128) y2s[tid - 64] = nsum;
    __syncthreads();

    // read norms into regs BEFORE LDS reuse
    float xs2[4], ys2[4];
    #pragma unroll
    for (int r = 0; r < 4; ++r) xs2[r] = x2s[ty * 4 + r];
    #pragma unroll
    for (int c = 0; c < 4; ++c) ys2[c] = y2s[tx * 4 + c];
    __syncthreads();

    // stage into sheared LDS tile: Zt[u_rel][iLoc], u_rel = 4tx + c + (ty>>1)
    float* Zt = smem;                     // [71][65]
    const int sb = ty >> 1;
    #pragma unroll
    for (int r = 0; r < 4; ++r)
        #pragma unroll
        for (int c = 0; c < 4; ++c)
            Zt[(4 * tx + c + sb) * 65 + (4 * ty + r)] = xs2[r] + ys2[c] - 2.f * acc[r][c];
    __syncthreads();

    // coalesced u-row stores: u_global = j0 + 8ti + w, 64 contiguous floats at i0
    const int w0 = tid >> 6;              // wave id 0..3
    const int lane = tid & 63;
    const int iGlob = i0 + lane;
    const int sbl = lane >> 3;            // s(i) - 8ti
    const bool iok = iGlob < T_;
    const size_t ub = (size_t)(j0 + 8 * ti) * 800 + iGlob;
    #pragma unroll
    for (int it = 0; it < 18; ++it) {
        int w = w0 + it * 4;
        if (w > 70) break;
        int jrel = w - sbl;
        if (iok && (unsigned)jrel < 64u && (j0 + jrel) < T_)
            Dm[(size_t)kb * SLAB_ + ub + (size_t)w * 800] = Zt[w * 65 + lane];
    }
}

// ---------------------------------------------------------------- single-wave hard-min DTW, r=16, g=8 shear
// One wave per problem: zero barriers/LDS. Lane l rows 16l..16l+15 in two
// independent 8-chains per step.
//
// R13 cell compression: n = min3(dg, up+W, left+W) + D; carry s (raw) and
// w = s+W -> 3 VALU/cell (v_min3, +D, +W).
//
// R14: restore "memory" clobber on the counted vmcnt waits (R13 dropped it;
// compiler sank loads to uses -> VGPR 80, ring collapsed, ~40 extra
// mov/addr insts per step). Also: med3 clamp + 32-bit saddr-form offsets
// (uniform base + v_off, offset:0/16/32/48) -> addressing ~3 VALU/step.
__device__ __forceinline__ float wave_shr1(float x) {
    int v = __builtin_amdgcn_update_dpp(0, __float_as_int(x), 0x138, 0xf, 0xf, true);
    return __int_as_float(v);
}

#define WAITV(n) asm volatile("s_waitcnt vmcnt(" #n ")" ::: "memory")

__global__ __launch_bounds__(64, 1) void dtw_wave_kernel(const float* __restrict__ Dm,
                                                         float* __restrict__ dtwv) {
    const int kb = blockIdx.x;
    const int l  = threadIdx.x;
    const int lc = l < 49 ? l : 49;             // lanes 50-63 mirror lane 49
    const bool is_l0 = (l == 0);
    const float* __restrict__ Dd = Dm + (size_t)kb * SLAB_;

    const int ti_l = lc >> 2;
    const int Jlo = ti_l >= 2 ? 64 * (ti_l - 2) : 0;
    const int Jhi = min(799, 64 * ti_l + 191);
    const int lo_u = (Jlo == 0) ? (2 * lc) : (Jlo + 2 * lc + 1);
    const int hi_u = Jhi + 2 * lc + 1;
    const unsigned lofs = (unsigned)(lc << 4);

    // DP state: raw values s0..s15 and pre-added w_i = s_i + WARP
    float s0 = BIGV, s1 = BIGV, s2 = BIGV, s3 = BIGV, s4 = BIGV, s5 = BIGV, s6 = BIGV, s7 = BIGV;
    float s8 = BIGV, s9 = BIGV, s10 = BIGV, s11 = BIGV, s12 = BIGV, s13 = BIGV, s14 = BIGV, s15 = BIGV;
    float w0 = BIGV, w1 = BIGV, w2 = BIGV, w3 = BIGV, w4 = BIGV, w5 = BIGV, w6 = BIGV, w7 = BIGV;
    float w8 = BIGV, w9 = BIGV, w10 = BIGV, w11 = BIGV, w12 = BIGV, w13 = BIGV, w14 = BIGV, w15 = BIGV;
    float s7p = BIGV;                           // raw S7 two steps ago
    float tinA = BIGV;                          // lane l-1 raw S15, one step ago
    float tinAW = BIGV;                         // tinA + WARP
    float tinB = is_l0 ? 0.f : BIGV;            // raw, two steps ago (lane0: diag of (0,0))

    auto pref = [&](float4 (&sl)[4], int uu) {
        int uc = min(max(uu, lo_u), hi_u);      // v_med3_i32
        unsigned off = (unsigned)(uc * 800) + lofs;   // elements; fits 32-bit
        const float4* p = (const float4*)(Dd + off);  // uniform base + 32b voffset
        sl[0] = p[0];
        sl[1] = p[1];
        sl[2] = p[2];
        sl[3] = p[3];
    };

    auto step = [&](const float4 (&dq)[4]) {
        const float up7 = s7;                   // raw S7 pre-update (s7p next step)
        float d0 = tinB, uw0 = tinAW;           // chain-0 inputs (diag raw, up+W)
        float d1 = s7p,  uw1 = w7;              // chain-1 inputs (w7 pre-update)
        #define CELLP(SA, WA, DA, SB, WB, DB)                          \
        {   float mA = fminf(fminf(d0, uw0), WA);  /* v_min3 */        \
            float nA = mA + (DA);                                      \
            d0 = SA; SA = nA;                                          \
            float tA = nA + WARP_V; uw0 = tA; WA = tA;                 \
            float mB = fminf(fminf(d1, uw1), WB);                      \
            float nB = mB + (DB);                                      \
            d1 = SB; SB = nB;                                          \
            float tB = nB + WARP_V; uw1 = tB; WB = tB;                 \
        }
        CELLP(s0, w0, dq[0].x, s8,  w8,  dq[2].x);
        CELLP(s1, w1, dq[0].y, s9,  w9,  dq[2].y);
        CELLP(s2, w2, dq[0].z, s10, w10, dq[2].z);
        CELLP(s3, w3, dq[0].w, s11, w11, dq[2].w);
        CELLP(s4, w4, dq[1].x, s12, w12, dq[3].x);
        CELLP(s5, w5, dq[1].y, s13, w13, dq[3].y);
        CELLP(s6, w6, dq[1].z, s14, w14, dq[3].z);
        CELLP(s7, w7, dq[1].w, s15, w15, dq[3].w);
        #undef CELLP
        s7p = up7;
        float hand = wave_shr1(s15);
        tinB = tinA;
        tinA = is_l0 ? BIGV : hand;
        tinAW = tinA + WARP_V;
    };

    float4 q0[4], q1[4], q2[4], q3[4], q4[4], q5[4];
    pref(q0, 0); pref(q1, 1); pref(q2, 2); pref(q3, 3); pref(q4, 4); pref(q5, 5);

    int u = 0;
    for (int g = 0; g < 149; ++g) {             // steps 0..893
        WAITV(20); step(q0); pref(q0, u + 6);
        WAITV(20); step(q1); pref(q1, u + 7);
        WAITV(20); step(q2); pref(q2, u + 8);
        WAITV(20); step(q3); pref(q3, u + 9);
        WAITV(20); step(q4); pref(q4, u + 10);
        WAITV(20); step(q5); pref(q5, u + 11);
        u += 6;
    }
    // u = 894: slots hold steps 894..899 (>=899 clamped duplicates, unused lanes)
    WAITV(20); step(q0);                        // 894
    WAITV(16); step(q1);                        // 895
    WAITV(12); step(q2);                        // 896
    WAITV(8);  step(q3);                        // 897
    WAITV(4);  step(q4);                        // 898: lane 49 s15 = R[800][800]

    if (l == 49) dtwv[kb] = s15;
}

// ---------------------------------------------------------------- finalize (scalars)
__global__ void finalize_kernel(const float* __restrict__ dtwv, const int* __restrict__ mel_lens,
                                const int* __restrict__ src_lens, const float* __restrict__ durations,
                                const float* __restrict__ mus, const float* __restrict__ log_vars,
                                const int* __restrict__ step, float* __restrict__ out) {
    const int lane = threadIdx.x;  // 64 threads, one wave

    float v = (lane < KB_) ? dtwv[lane] : 0.f;
    for (int o = 32; o; o >>= 1) v += __shfl_down(v, o);

    float w = (lane < B_) ? 1.f / (K_ * (float)mel_lens[lane]) : 0.f;
    for (int o = 32; o; o >>= 1) w += __shfl_down(w, o);

    float du = 0.f;
    if (lane < B_) {
        float s = 0.f;
        for (int j = 0; j < S_; ++j) s += durations[lane * S_ + j];
        du = fabsf(s - (float)mel_lens[lane]) / (float)src_lens[lane];
    }
    for (int o = 32; o; o >>= 1) du += __shfl_down(du, o);

    float kl = 0.f;
    for (int j = lane; j < B_ * Z_; j += 64) {
        float muv = mus[j], lv = log_vars[j];
        kl += 1.f + lv - muv * muv - expf(lv);
    }
    for (int o = 32; o; o >>= 1) kl += __shfl_down(kl, o);

    if (lane == 0) {
        float mel_iter_loss = v / (float)B_;
        float mel_loss = mel_iter_loss * (w / (float)B_);
        float dur_loss = 2.0f * du / (float)B_;
        float kl_loss = -0.5f * kl;
        int st = step[0];
        float beta = (st < 2000) ? 0.f : ((st >= 8000) ? 1.f : (float)(st - 2000) / 6000.f);
        out[0] = mel_loss + dur_loss + beta * kl_loss;
        out[1] = mel_loss;
        out[2] = dur_loss;
        out[3] = kl_loss;
        out[4] = beta;
    }
}

// ---------------------------------------------------------------- launch
extern "C" void kernel_launch(void* const* d_in, const int* in_sizes, int n_in,
                              void* d_out, int out_size, void* d_ws, size_t ws_size,
                              hipStream_t stream) {
    const float* mel_iters   = (const float*)d_in[0];
    const float* mel_targets = (const float*)d_in[1];
    const int*   mel_lens    = (const int*)d_in[2];
    const int*   src_lens    = (const int*)d_in[3];
    const float* durations   = (const float*)d_in[4];
    const float* mus         = (const float*)d_in[5];
    const float* log_vars    = (const float*)d_in[6];
    const int*   step        = (const int*)d_in[7];
    float* out = (float*)d_out;

    float* ws   = (float*)d_ws;
    float* Dm   = ws;                              // 32 * 720,000 floats = 92.16 MB
    float* dtwv = Dm + (size_t)KB_ * SLAB_;        //        32

    fill_edge<<<KB_, 192, 0, stream>>>(Dm);

    gemm_band<<<dim3(5, 13, KB_), 256, 0, stream>>>(mel_iters, mel_targets, Dm);

    dtw_wave_kernel<<<KB_, 64, 0, stream>>>(Dm, dtwv);

    finalize_kernel<<<1, 64, 0, stream>>>(dtwv, mel_lens, src_lens, durations, mus, log_vars, step, out);
}